// Round 10
// baseline (2134.421 us; speedup 1.0000x reference)
//
#include <hip/hip_runtime.h>
#include <hip/hip_bf16.h>
#include <stdint.h>

#define T_TOK 8192
#define DIM   2048
#define NEXP  8
#define HDIM  1408
#define SHDIM 2816

typedef __attribute__((ext_vector_type(8))) short bfrag;   // 8 x bf16 (4 VGPR)
typedef __attribute__((ext_vector_type(4))) float f32x4;
typedef __attribute__((ext_vector_type(4))) short s16x4;

__device__ __forceinline__ short f2bf(float f) {
    union { float f; uint32_t u; } v; v.f = f;
    return (short)((v.u + 0x8000u) >> 16);   // round-half-up bf16
}
__device__ __forceinline__ float bf2f(short s) {
    union { uint32_t u; float f; } v; v.u = ((uint32_t)(uint16_t)s) << 16;
    return v.f;
}

__device__ __forceinline__ bfrag cvt8(float4 a, float4 b) {
    bfrag r;
    r[0] = f2bf(a.x); r[1] = f2bf(a.y); r[2] = f2bf(a.z); r[3] = f2bf(a.w);
    r[4] = f2bf(b.x); r[5] = f2bf(b.y); r[6] = f2bf(b.z); r[7] = f2bf(b.w);
    return r;
}

__device__ __forceinline__ void gload16(const void* g, void* l) {
    __builtin_amdgcn_global_load_lds(
        (__attribute__((address_space(1))) void*)(g),
        (__attribute__((address_space(3))) void*)(l), 16, 0, 0);
}

#define MFMA16(a, b, c) __builtin_amdgcn_mfma_f32_16x16x32_bf16((a), (b), (c), 0, 0, 0)

// meta: ints [0..7] counts, [8..15] cursor, [16..24] offsets; floats at +32: s_e[8]

__global__ __launch_bounds__(256) void gate_kernel(
    const float* __restrict__ x, const float* __restrict__ gw,
    __hip_bfloat16* __restrict__ xbf,
    int* __restrict__ sel, int* __restrict__ meta, float* __restrict__ s_e)
{
    __shared__ float g[NEXP * DIM];            // 64 KB
    for (int i = threadIdx.x; i < NEXP * DIM; i += 256) g[i] = gw[i];
    __syncthreads();
    const int wid = threadIdx.x >> 6, lane = threadIdx.x & 63;
    for (int it = 0; it < 8; ++it) {
        const int t = blockIdx.x * 32 + wid * 8 + it;
        float acc[NEXP];
#pragma unroll
        for (int e = 0; e < NEXP; ++e) acc[e] = 0.f;
        const float4* xr = (const float4*)(x + (size_t)t * DIM);
        for (int j = 0; j < DIM / 4; j += 64) {
            float4 xv = xr[j + lane];
            s16x4 xv16 = { f2bf(xv.x), f2bf(xv.y), f2bf(xv.z), f2bf(xv.w) };
            *(s16x4*)&xbf[(size_t)t * DIM + (j + lane) * 4] = xv16;
#pragma unroll
            for (int e = 0; e < NEXP; ++e) {
                float4 gv = *(const float4*)&g[e * DIM + (j + lane) * 4];
                acc[e] += xv.x * gv.x + xv.y * gv.y + xv.z * gv.z + xv.w * gv.w;
            }
        }
#pragma unroll
        for (int e = 0; e < NEXP; ++e)
            for (int o = 32; o; o >>= 1) acc[e] += __shfl_xor(acc[e], o);
        if (lane == 0) {
            int e0 = 0; float v0 = acc[0];
#pragma unroll
            for (int e = 1; e < NEXP; ++e) if (acc[e] > v0) { v0 = acc[e]; e0 = e; }
            int e1 = -1; float v1 = -3.4e38f;
#pragma unroll
            for (int e = 0; e < NEXP; ++e) if (e != e0 && acc[e] > v1) { v1 = acc[e]; e1 = e; }
            float p0 = 1.f / (1.f + __expf(v1 - v0));
            float p1 = 1.f - p0;
            sel[2 * t] = e0; sel[2 * t + 1] = e1;
            atomicAdd(&s_e[e0], p0); atomicAdd(&s_e[e1], p1);
            atomicAdd(&meta[e0], 1); atomicAdd(&meta[e1], 1);
        }
    }
}

__global__ void scan_kernel(int* meta) {
    if (threadIdx.x == 0) {
        int acc = 0;
        for (int e = 0; e < NEXP; ++e) {
            meta[16 + e] = acc;
            meta[8 + e]  = acc;
            acc += meta[e];
        }
        meta[24] = acc;
    }
}

__global__ __launch_bounds__(256) void fill_kernel(
    const int* __restrict__ sel, int* __restrict__ meta,
    int* __restrict__ list, int2* __restrict__ slots)
{
    const int t = blockIdx.x * 256 + threadIdx.x;
    int e0 = sel[2 * t], e1 = sel[2 * t + 1];
    int p0 = atomicAdd(&meta[8 + e0], 1); list[p0] = t;
    int p1 = atomicAdd(&meta[8 + e1], 1); list[p1] = t;
    slots[t] = make_int2(p0, p1);
}

// fp32->bf16 for w1,w3,sw1,sw3 (w2/sw2 converted inside UP's tail workers)
#define D1 2883584
#define D2 5767168
#define D3 6488064
#define D4 7208960
__global__ __launch_bounds__(256) void cvt4_kernel(
    const float* __restrict__ s0, const float* __restrict__ s1,
    const float* __restrict__ s2, const float* __restrict__ s3,
    __hip_bfloat16* __restrict__ d0, __hip_bfloat16* __restrict__ d1,
    __hip_bfloat16* __restrict__ d2, __hip_bfloat16* __restrict__ d3)
{
    const int stride = gridDim.x * 256;
    for (int i = blockIdx.x * 256 + threadIdx.x; i < D4; i += stride) {
        const float* s; __hip_bfloat16* d; int off;
        if      (i < D1) { s = s0; d = d0; off = i; }
        else if (i < D2) { s = s1; d = d1; off = i - D1; }
        else if (i < D3) { s = s2; d = d2; off = i - D2; }
        else             { s = s3; d = d3; off = i - D3; }
        const float4* p = (const float4*)(s + (size_t)off * 8);
        float4 a = p[0], b = p[1];
        *(bfrag*)(d + (size_t)off * 8) = cvt8(a, b);
    }
}

// =================== merged UP: shared + expert gate/up GEMMs ===================
// R3-structure dbuf K-loop (best measured). Tile map over swizzled virt id:
//   virt < ns  : shared tile (N=SHDIM, nx=22, SW1/SW3, count=T_TOK) -> act_sh
//   else       : expert tile (N=HDIM, nx=11, W1/W3, gathered rows)   -> act_ex
// bid >= ns+ne : cvt worker for w2/sw2 (runs in the dispatch tail).
#define W2ELEMS 23068672   // 8*2048*1408
#define CVTCHUNKS 7040     // (w2 + sw2 elems) / 4096

__global__ __launch_bounds__(512, 2) void up_merged(
    const __hip_bfloat16* __restrict__ X,
    const __hip_bfloat16* __restrict__ W1,  const __hip_bfloat16* __restrict__ W3,
    const __hip_bfloat16* __restrict__ SW1, const __hip_bfloat16* __restrict__ SW3,
    __hip_bfloat16* __restrict__ act_sh,    // [T_TOK][SHDIM]
    __hip_bfloat16* __restrict__ act_ex,    // [2*T_TOK][HDIM]
    const int* __restrict__ list, const int* __restrict__ meta,
    const float* __restrict__ w2f, const float* __restrict__ sw2f,
    __hip_bfloat16* __restrict__ w2bf, __hip_bfloat16* __restrict__ sw2bf,
    int ns, int ne, int ncvt)
{
    constexpr int K = DIM;
    constexpr int NT = K / 64;
    const int tid = threadIdx.x, bid = blockIdx.x;

    if (bid >= ns + ne) {            // ---- cvt worker (w2, sw2) ----
        for (int c = bid - (ns + ne); c < CVTCHUNKS; c += ncvt) {
            size_t elem = (size_t)c * 4096 + tid * 8;
            const float* s; __hip_bfloat16* d;
            if (elem < W2ELEMS) { s = w2f + elem; d = w2bf + elem; }
            else { s = sw2f + (elem - W2ELEMS); d = sw2bf + (elem - W2ELEMS); }
            float4 a = ((const float4*)s)[0], b = ((const float4*)s)[1];
            *(bfrag*)d = cvt8(a, b);
        }
        return;
    }

    const int cpx = (ns + ne) >> 3;
    const int virt = (bid & 7) * cpx + (bid >> 3);

    int N, n0, m0, count, base;
    const __hip_bfloat16 *B1p, *B3p;
    __hip_bfloat16* actp;
    bool gather;
    if (virt < ns) {
        N = SHDIM; gather = false;
        n0 = (virt % 22) * 128; m0 = (virt / 22) * 256;
        count = T_TOK; base = 0;
        B1p = SW1; B3p = SW3; actp = act_sh;
    } else {
        const int t = virt - ns;
        const int e = t / 352, r = t % 352;
        N = HDIM; gather = true;
        n0 = (r % 11) * 128; m0 = (r / 11) * 256;
        count = meta[e]; base = meta[16 + e];
        if (m0 >= count) return;
        B1p = W1 + (size_t)e * HDIM * K;
        B3p = W3 + (size_t)e * HDIM * K;
        actp = act_ex;
    }

    __shared__ alignas(16) short As[2][256 * 64];    // 64 KB
    __shared__ alignas(16) short B1s[2][128 * 64];   // 32 KB
    __shared__ alignas(16) short B3s[2][128 * 64];   // 32 KB

    const int wid = tid >> 6, lane = tid & 63;
    const int rlo = lane >> 3;               // row within 8-row chunk
    const int swslot = (lane & 7) ^ rlo;     // pre-swizzled source 16B slot

    const __hip_bfloat16* pA[4];
#pragma unroll
    for (int q = 0; q < 4; ++q) {
        int row = (q * 8 + wid) * 8 + rlo;   // 0..255
        int r = m0 + row; if (r > count - 1) r = count - 1;
        int ga = gather ? list[base + r] : r;
        pA[q] = X + (size_t)ga * K + swslot * 8;
    }
    const __hip_bfloat16* pB1[2];
    const __hip_bfloat16* pB3[2];
#pragma unroll
    for (int q = 0; q < 2; ++q) {
        int row = (q * 8 + wid) * 8 + rlo;   // 0..127
        pB1[q] = B1p + (size_t)(n0 + row) * K + swslot * 8;
        pB3[q] = B3p + (size_t)(n0 + row) * K + swslot * 8;
    }

#define STAGE_UP(T, BUF) do { const int k0_ = (T) * 64;                         \
    _Pragma("unroll") for (int q = 0; q < 4; ++q)                               \
        gload16(pA[q] + k0_, &As[BUF][(q * 8 + wid) * 512]);                    \
    _Pragma("unroll") for (int q = 0; q < 2; ++q) {                             \
        gload16(pB1[q] + k0_, &B1s[BUF][(q * 8 + wid) * 512]);                  \
        gload16(pB3[q] + k0_, &B3s[BUF][(q * 8 + wid) * 512]); } } while (0)

    const int wm = wid >> 2, wn = wid & 3;
    const int l15 = lane & 15, lhi = lane >> 4;

    f32x4 accg[8][2], accu[8][2];
#pragma unroll
    for (int i = 0; i < 8; ++i)
#pragma unroll
        for (int j = 0; j < 2; ++j) { accg[i][j] = 0.f; accu[i][j] = 0.f; }

    STAGE_UP(0, 0);
    __syncthreads();                         // drains vmcnt: tile 0 landed
    int cur = 0;
#pragma unroll 1
    for (int t = 0; t < NT; ++t) {
        if (t + 1 < NT) STAGE_UP(t + 1, cur ^ 1);
        __builtin_amdgcn_sched_barrier(0);   // pin stage issue before reads
        bfrag b1f[2][2], b3f[2][2];
#pragma unroll
        for (int j = 0; j < 2; ++j)
#pragma unroll
            for (int kk = 0; kk < 2; ++kk) {
                int rb = wn * 32 + j * 16 + l15;
                int c = kk * 4 + lhi;
                int off = rb * 128 + ((c ^ (rb & 7)) << 4);
                b1f[j][kk] = *(const bfrag*)((const char*)B1s[cur] + off);
                b3f[j][kk] = *(const bfrag*)((const char*)B3s[cur] + off);
            }
        __builtin_amdgcn_s_setprio(1);
#pragma unroll
        for (int i = 0; i < 8; ++i) {
            int ra = wm * 128 + i * 16 + l15;
            const char* abase = (const char*)As[cur] + ra * 128;
            bfrag a0 = *(const bfrag*)(abase + ((lhi       ^ (ra & 7)) << 4));
            bfrag a1 = *(const bfrag*)(abase + (((4 + lhi) ^ (ra & 7)) << 4));
#pragma unroll
            for (int j = 0; j < 2; ++j) {
                accg[i][j] = MFMA16(a0, b1f[j][0], accg[i][j]);
                accu[i][j] = MFMA16(a0, b3f[j][0], accu[i][j]);
                accg[i][j] = MFMA16(a1, b1f[j][1], accg[i][j]);
                accu[i][j] = MFMA16(a1, b3f[j][1], accu[i][j]);
            }
        }
        __builtin_amdgcn_s_setprio(0);
        __syncthreads();                     // drain: tile t+1 landed
        cur ^= 1;
    }
#undef STAGE_UP

#pragma unroll
    for (int i = 0; i < 8; ++i)
#pragma unroll
        for (int r = 0; r < 4; ++r) {
            int m = wm * 128 + i * 16 + lhi * 4 + r;
            if (m0 + m < count) {
#pragma unroll
                for (int j = 0; j < 2; ++j) {
                    float gg = accg[i][j][r];
                    float uu = accu[i][j][r];
                    float a = gg / (1.f + __expf(-gg)) * uu;   // silu(g)*u
                    int n = n0 + wn * 32 + j * 16 + l15;
                    actp[(size_t)(base + m0 + m) * N + n] = __float2bfloat16(a);
                }
            }
        }
}

// =================== merged DOWN: shared + expert down GEMMs ===================
//   virt < ns  : shared (A=act_sh, KD=SHDIM, B=SW2, f32 -> out)
//   else       : expert (A=act_ex, KD=HDIM, B=W2[e], bf16 -> yscr)
__global__ __launch_bounds__(512, 2) void down_merged(
    const __hip_bfloat16* __restrict__ act_sh,
    const __hip_bfloat16* __restrict__ act_ex,
    const __hip_bfloat16* __restrict__ W2, const __hip_bfloat16* __restrict__ SW2,
    float* __restrict__ out, __hip_bfloat16* __restrict__ yscr,
    const int* __restrict__ meta, int ns, int ne)
{
    constexpr int N = DIM;
    const int tid = threadIdx.x, bid = blockIdx.x;
    const int cpx = (ns + ne) >> 3;
    const int virt = (bid & 7) * cpx + (bid >> 3);

    int KD, n0, m0, count, base;
    const __hip_bfloat16 *Ap, *Bp;
    bool tobf;
    if (virt < ns) {
        KD = SHDIM; tobf = false;
        n0 = (virt % 8) * 256; m0 = (virt / 8) * 256;
        count = T_TOK; base = 0;
        Ap = act_sh; Bp = SW2;
    } else {
        const int t = virt - ns;
        const int e = t / 256, r = t % 256;
        KD = HDIM; tobf = true;
        n0 = (r % 8) * 256; m0 = (r / 8) * 256;
        count = meta[e]; base = meta[16 + e];
        if (m0 >= count) return;
        Ap = act_ex; Bp = W2 + (size_t)e * N * HDIM;
    }
    const int NT = KD / 64;

    __shared__ alignas(16) short As[2][256 * 64];    // 64 KB
    __shared__ alignas(16) short Bs[2][256 * 64];    // 64 KB

    const int wid = tid >> 6, lane = tid & 63;
    const int rlo = lane >> 3;
    const int swslot = (lane & 7) ^ rlo;

    const __hip_bfloat16* pA[4];
    const __hip_bfloat16* pB[4];
#pragma unroll
    for (int q = 0; q < 4; ++q) {
        int row = (q * 8 + wid) * 8 + rlo;   // 0..255
        int r = m0 + row; if (r > count - 1) r = count - 1;
        pA[q] = Ap + (size_t)(base + r) * KD + swslot * 8;
        pB[q] = Bp + (size_t)(n0 + row) * KD + swslot * 8;
    }

#define STAGE_DN(T, BUF) do { const int k0_ = (T) * 64;                         \
    _Pragma("unroll") for (int q = 0; q < 4; ++q) {                             \
        gload16(pA[q] + k0_, &As[BUF][(q * 8 + wid) * 512]);                    \
        gload16(pB[q] + k0_, &Bs[BUF][(q * 8 + wid) * 512]); } } while (0)

    const int wm = wid >> 2, wn = wid & 3;
    const int l15 = lane & 15, lhi = lane >> 4;

    f32x4 acc[8][4];
#pragma unroll
    for (int i = 0; i < 8; ++i)
#pragma unroll
        for (int j = 0; j < 4; ++j) acc[i][j] = 0.f;

    STAGE_DN(0, 0);
    __syncthreads();
    int cur = 0;
#pragma unroll 1
    for (int t = 0; t < NT; ++t) {
        if (t + 1 < NT) STAGE_DN(t + 1, cur ^ 1);
        __builtin_amdgcn_sched_barrier(0);
        bfrag bf[4][2];
#pragma unroll
        for (int j = 0; j < 4; ++j)
#pragma unroll
            for (int kk = 0; kk < 2; ++kk) {
                int rb = wn * 64 + j * 16 + l15;
                int c = kk * 4 + lhi;
                bf[j][kk] = *(const bfrag*)((const char*)Bs[cur] + rb * 128 + ((c ^ (rb & 7)) << 4));
            }
        __builtin_amdgcn_s_setprio(1);
#pragma unroll
        for (int i = 0; i < 8; ++i) {
            int ra = wm * 128 + i * 16 + l15;
            const char* abase = (const char*)As[cur] + ra * 128;
            bfrag a0 = *(const bfrag*)(abase + ((lhi       ^ (ra & 7)) << 4));
            bfrag a1 = *(const bfrag*)(abase + (((4 + lhi) ^ (ra & 7)) << 4));
#pragma unroll
            for (int j = 0; j < 4; ++j) {
                acc[i][j] = MFMA16(a0, bf[j][0], acc[i][j]);
                acc[i][j] = MFMA16(a1, bf[j][1], acc[i][j]);
            }
        }
        __builtin_amdgcn_s_setprio(0);
        __syncthreads();
        cur ^= 1;
    }
#undef STAGE_DN

#pragma unroll
    for (int i = 0; i < 8; ++i)
#pragma unroll
        for (int r = 0; r < 4; ++r) {
            int m = wm * 128 + i * 16 + lhi * 4 + r;
            if (m0 + m < count) {
#pragma unroll
                for (int j = 0; j < 4; ++j) {
                    int n = n0 + wn * 64 + j * 16 + l15;
                    if (tobf)
                        yscr[(size_t)(base + m0 + m) * DIM + n] = __float2bfloat16(acc[i][j][r]);
                    else
                        out[(size_t)(m0 + m) * DIM + n] = acc[i][j][r];
                }
            }
        }
}

// out[t] += s_e[e0]*y[slot0] + s_e[e1]*y[slot1]
__global__ __launch_bounds__(256) void combine_kernel(
    float* __restrict__ out, const __hip_bfloat16* __restrict__ yscr,
    const int* __restrict__ sel, const int2* __restrict__ slots,
    const float* __restrict__ s_e)
{
    const int t = blockIdx.x;
    const int d = threadIdx.x * 8;
    const int2 sl = slots[t];
    const float se0 = s_e[sel[2 * t]];
    const float se1 = s_e[sel[2 * t + 1]];
    bfrag y0 = *(const bfrag*)&yscr[(size_t)sl.x * DIM + d];
    bfrag y1 = *(const bfrag*)&yscr[(size_t)sl.y * DIM + d];
    float4* o = (float4*)(out + (size_t)t * DIM + d);
    float4 o0 = o[0], o1 = o[1];
    o0.x += se0 * bf2f(y0[0]) + se1 * bf2f(y1[0]);
    o0.y += se0 * bf2f(y0[1]) + se1 * bf2f(y1[1]);
    o0.z += se0 * bf2f(y0[2]) + se1 * bf2f(y1[2]);
    o0.w += se0 * bf2f(y0[3]) + se1 * bf2f(y1[3]);
    o1.x += se0 * bf2f(y0[4]) + se1 * bf2f(y1[4]);
    o1.y += se0 * bf2f(y0[5]) + se1 * bf2f(y1[5]);
    o1.z += se0 * bf2f(y0[6]) + se1 * bf2f(y1[6]);
    o1.w += se0 * bf2f(y0[7]) + se1 * bf2f(y1[7]);
    o[0] = o0; o[1] = o1;
}

extern "C" void kernel_launch(void* const* d_in, const int* in_sizes, int n_in,
                              void* d_out, int out_size, void* d_ws, size_t ws_size,
                              hipStream_t stream) {
    const float* x   = (const float*)d_in[0];
    const float* gw  = (const float*)d_in[1];
    const float* w1  = (const float*)d_in[2];
    const float* w3  = (const float*)d_in[3];
    const float* w2  = (const float*)d_in[4];
    const float* sw1 = (const float*)d_in[5];
    const float* sw3 = (const float*)d_in[6];
    const float* sw2 = (const float*)d_in[7];
    float* out = (float*)d_out;

    const size_t SZ_X    = (size_t)T_TOK * DIM * 2;           // 33.6 MB
    const size_t SZ_W    = (size_t)NEXP * HDIM * DIM * 2;     // 46.1 MB each
    const size_t SZ_SW   = (size_t)SHDIM * DIM * 2;           // 11.5 MB each
    const size_t SZ_ACTS = (size_t)T_TOK * SHDIM * 2;         // 46.1 MB
    const size_t SZ_ACTE = (size_t)2 * T_TOK * HDIM * 2;      // 46.1 MB
    const size_t SZ_INTS = (size_t)6 * T_TOK * sizeof(int) + 512;

    const size_t need_base   = SZ_X + 3 * SZ_W + 3 * SZ_SW + SZ_ACTS + SZ_INTS; // ~253 MB (known OK)
    const size_t need_merged = need_base + SZ_ACTE;                              // ~299 MB

    char* p = (char*)d_ws;
    __hip_bfloat16* xbf   = (__hip_bfloat16*)p; p += SZ_X;
    __hip_bfloat16* w1bf  = (__hip_bfloat16*)p; p += SZ_W;
    __hip_bfloat16* w3bf  = (__hip_bfloat16*)p; p += SZ_W;
    __hip_bfloat16* w2bf  = (__hip_bfloat16*)p; p += SZ_W;
    __hip_bfloat16* sw1bf = (__hip_bfloat16*)p; p += SZ_SW;
    __hip_bfloat16* sw3bf = (__hip_bfloat16*)p; p += SZ_SW;
    __hip_bfloat16* sw2bf = (__hip_bfloat16*)p; p += SZ_SW;
    __hip_bfloat16* act_sh = (__hip_bfloat16*)p; p += SZ_ACTS;
    const bool merged = (need_merged <= ws_size);
    __hip_bfloat16* act_ex = merged ? (__hip_bfloat16*)p : act_sh;   // fallback: alias
    if (merged) p += SZ_ACTE;
    int*  list  = (int*)p;  p += (size_t)2 * T_TOK * sizeof(int);
    int*  sel   = (int*)p;  p += (size_t)2 * T_TOK * sizeof(int);
    int2* slots = (int2*)p; p += (size_t)2 * T_TOK * sizeof(int);
    int*  meta  = (int*)p;
    float* s_e  = (float*)(meta + 32);
    // yscr (64 MB) aliases w1bf+w3bf (92 MB, dead once UP completes)
    __hip_bfloat16* yscr = w1bf;
    if (need_base > ws_size) return;

    hipMemsetAsync(meta, 0, 256, stream);
    gate_kernel<<<T_TOK / 32, 256, 0, stream>>>(x, gw, xbf, sel, meta, s_e);
    scan_kernel<<<1, 64, 0, stream>>>(meta);
    fill_kernel<<<T_TOK / 256, 256, 0, stream>>>(sel, meta, list, slots);
    cvt4_kernel<<<2048, 256, 0, stream>>>(w1, w3, sw1, sw3, w1bf, w3bf, sw1bf, sw3bf);

    const int NS_U = 704, NE_U = 2816, NCVT = 220;
    const int NS_D = 256, NE_D = 2048;

    if (merged) {
        up_merged<<<NS_U + NE_U + NCVT, 512, 0, stream>>>(
            xbf, w1bf, w3bf, sw1bf, sw3bf, act_sh, act_ex, list, meta,
            w2, sw2, w2bf, sw2bf, NS_U, NE_U, NCVT);
        down_merged<<<NS_D + NE_D, 512, 0, stream>>>(
            act_sh, act_ex, w2bf, sw2bf, out, yscr, meta, NS_D, NE_D);
    } else {
        // sequential fallback (R7 ordering, act shared): cvt w2/sw2 rides UP-shared
        up_merged<<<NS_U + NCVT, 512, 0, stream>>>(
            xbf, w1bf, w3bf, sw1bf, sw3bf, act_sh, act_ex, list, meta,
            w2, sw2, w2bf, sw2bf, NS_U, 0, NCVT);
        down_merged<<<NS_D, 512, 0, stream>>>(
            act_sh, act_ex, w2bf, sw2bf, out, yscr, meta, NS_D, 0);
        up_merged<<<NE_U, 512, 0, stream>>>(
            xbf, w1bf, w3bf, sw1bf, sw3bf, act_sh, act_ex, list, meta,
            w2, sw2, w2bf, sw2bf, 0, NE_U, 0);
        down_merged<<<NE_D, 512, 0, stream>>>(
            act_sh, act_ex, w2bf, sw2bf, out, yscr, meta, 0, NE_D);
    }
    combine_kernel<<<T_TOK, 256, 0, stream>>>(out, yscr, sel, slots, s_e);
}